// Round 9
// baseline (510.331 us; speedup 1.0000x reference)
//
#include <hip/hip_runtime.h>

#define ROWSB 16     // rows per block; 4 waves x 4 rows -> 4096 waves = 4/SIMD
#define HIDN 256
#define TT 8
#define EPSI 1e-6f
#define HAS 260      // ha/vbuf row stride (floats)
#define SVS 260      // sorted-vocab row stride in ws (257 used + 3 INF pad)
#define TBSTR 40
#define NCELL 512
#define WS_LUT_F   (32*SVS)                 // ushort lut[32][512] == 8192 floats
#define WS_DINFO_F (32*SVS + 8192)          // float2 dinfo[32] (base, scale)
#define WS_WMV_F   (32*SVS + 8192 + 64)     // interleaved [j][d][(mu,var)] = 16384 floats

__device__ __forceinline__ void ld4(float* d, const float* p) {
  float4 v = *(const float4*)p;
  d[0] = v.x; d[1] = v.y; d[2] = v.z; d[3] = v.w;
}
__device__ __forceinline__ void ld2(float* d, const float* p) {
  float2 v = *(const float2*)p;
  d[0] = v.x; d[1] = v.y;
}
// Order own-wave LDS write->read without draining the global-load (vmcnt) queue.
__device__ __forceinline__ void lds_fence() {
  asm volatile("s_waitcnt lgkmcnt(0)" ::: "memory");
}
// 4 FMAs for one j, one row: wv = (mu[d0],var[d0],mu[d1],var[d1]); h = ha[row][j]
__device__ __forceinline__ void fma4(float4 wv, float h, float* mu, float* lv) {
  mu[0] += h*wv.x; lv[0] += h*wv.y; mu[1] += h*wv.z; lv[1] += h*wv.w;
}

// ---------- pre-pass: per-dim bitonic sort + 512-cell LUT + (mu,var) weight interleave ----------
__global__ __launch_bounds__(256)
void sort_vocab(const float* __restrict__ vocab,
                const float* __restrict__ Wmu, const float* __restrict__ Wvar,
                float* __restrict__ ws) {
  __shared__ float arr[512];
  const int d = blockIdx.x;
  const int t = threadIdx.x;
  ws[WS_WMV_F + ((size_t)t*32 + d)*2 + 0] = Wmu[(size_t)t*32 + d];
  ws[WS_WMV_F + ((size_t)t*32 + d)*2 + 1] = Wvar[(size_t)t*32 + d];
  arr[t] = (t < 257) ? vocab[t*32 + d] : 3.0e38f;
  arr[t+256] = (t == 0) ? vocab[256*32 + d] : 3.0e38f;
  __syncthreads();
  for (int k = 2; k <= 512; k <<= 1) {
    for (int j = k >> 1; j > 0; j >>= 1) {
      #pragma unroll
      for (int h = 0; h < 2; ++h) {
        int i = t + h*256;
        int ixj = i ^ j;
        if (ixj > i) {
          float a = arr[i], b = arr[ixj];
          bool up = ((i & k) == 0);
          if ((a > b) == up) { arr[i] = b; arr[ixj] = a; }
        }
      }
      __syncthreads();
    }
  }
  #pragma unroll
  for (int h = 0; h < 2; ++h) {
    int i = t + h*256;
    if (i < SVS) ws[d*SVS + i] = (i < 257) ? arr[i] : 3.0e38f;
  }
  float base = arr[0];
  float maxv = arr[256];
  float scale = (float)NCELL / fmaxf(maxv - base, 1e-30f);
  if (t == 0) {
    float2* dinfo = (float2*)(ws + WS_DINFO_F);
    dinfo[d] = make_float2(base, scale);
  }
  #pragma unroll
  for (int h = 0; h < 2; ++h) {
    int cell = t + h*256;
    float target = base + (float)cell * (maxv - base) * (1.0f/(float)NCELL);
    int lo = 0, hi = 257;
    while (lo < hi) { int mid = (lo+hi)>>1; if (arr[mid] < target) lo = mid+1; else hi = mid; }
    ((unsigned short*)(ws + WS_LUT_F))[d*NCELL + cell] = (unsigned short)lo;
  }
}

// ---------- main fused kernel: 4 rows/wave -> 4 waves/SIMD; N=2 cap fits demand ----------
// r8 = r1's correctness-validated structure with ONLY the launch_bounds fixed.
// REGISTER LAW (r0-r7): arch-VGPR cap = 256/arg2; HW occupancy follows TOTAL unified
// (arch+acc) regs: 4 waves/SIMD needs total <=128. r1 died from arg2=4 -> cap 64 ->
// ~50 hot regs scratch-spilled per iter (155MB FETCH). True demand here is ~115
// (48 persistent Qr/Kr/MSGr + 32 GEMV dbuf + temps) -> fits cap 128 with N=2, and
// total ~<=128 keeps the full 4 waves/SIMD that this decomposition's 4096 waves
// provide (8-rows/wave pins the chip at 2/SIMD -- r7's structural ceiling).
// LDS 36,352B -> 4 blocks/CU; grid 1024 = exactly 4/CU.
__global__ __launch_bounds__(256, 2)
void mac_fused(const float* __restrict__ hs, const float* __restrict__ eps,
               const float* __restrict__ WQ, const float* __restrict__ bQ,
               const float* __restrict__ WK, const float* __restrict__ bK,
               const float* __restrict__ Wmu, const float* __restrict__ bmu,
               const float* __restrict__ Wvar, const float* __restrict__ bvar,
               const float* __restrict__ vocab,
               const float* __restrict__ Wsum, const float* __restrict__ bsum,
               const float* __restrict__ Whead, const float* __restrict__ bhead,
               const float* __restrict__ ws, float* __restrict__ out, int Btot)
{
  // 36,352 B LDS -> 4 blocks/CU
  __shared__ __align__(16) float ha[ROWSB*HAS];       // wave-private rows; end: partial/o1 alias
  __shared__ __align__(16) float vbuf[ROWSB*HAS];     // V, wave-private, written once
  __shared__ __align__(16) float tokbuf[ROWSB*TBSTR]; // wave-private rows
  __shared__ float ivbuf[ROWSB], finbuf[ROWSB];       // wave-private rows

  const int t   = threadIdx.x;
  const int c4  = t & 63;
  const int w   = t >> 6;         // wave id; rows w*4..w*4+3
  const int rw  = w * 4;          // first block-row of this wave
  const int rp  = c4 >> 4;        // sampling row (within wave): 0..3
  const int dp  = c4 & 15;        // sampling dim-pair: dims 2dp, 2dp+1
  const int d0u = (c4 << 2) & 31;
  const int tg  = c4 >> 3;        // token slot of this thread's cols
  const int rowbase = blockIdx.x * ROWSB;

  float Qr[4][4], Kr[4][4], MSGr[4][4];
  float eosv[4];
  unsigned fin = 0u;

  // ---------------- staging (all wave-private) ----------------
  {
    const float* hp = hs + (size_t)(rowbase + rw)*HIDN + c4*4;
    #pragma unroll
    for (int rr = 0; rr < 4; ++rr)
      *(float4*)&ha[(rw+rr)*HAS + c4*4] = *(const float4*)(hp + (size_t)rr*HIDN);
  }
  if (c4 < 4) finbuf[rw + c4] = 0.f;
  ld4(eosv, vocab + 256*32 + d0u);
  float dbr[2], dsr[2];
  {
    float t0[4];
    ld4(t0, ws + WS_DINFO_F + dp*4);   // dinfo[2dp], dinfo[2dp+1]
    dbr[0]=t0[0]; dsr[0]=t0[1]; dbr[1]=t0[2]; dsr[1]=t0[3];
  }
  float bm[2], bv[2];
  ld2(bm, bmu + dp*2); ld2(bv, bvar + dp*2);
  lds_fence();   // own-wave ha writes ordered before cross-lane reads

  // ------------- initial GEMM: Q = hs@WQ + bQ ; V = hs@WK + bK (V -> vbuf) -------------
  {
    float Vr[4][4];
    {
      float bq[4], bk[4];
      ld4(bq, bQ + c4*4); ld4(bk, bK + c4*4);
      #pragma unroll
      for (int rr = 0; rr < 4; ++rr) {
        #pragma unroll
        for (int k = 0; k < 4; ++k) { Qr[rr][k] = bq[k]; Vr[rr][k] = bk[k]; }
      }
    }
    #pragma unroll 2
    for (int jq = 0; jq < 64; ++jq) {
      float hsq[4][4];
      #pragma unroll
      for (int rr = 0; rr < 4; ++rr) ld4(hsq[rr], &ha[(rw+rr)*HAS + jq*4]);
      #pragma unroll
      for (int m = 0; m < 4; ++m) {
        float wq[4], wk[4];
        ld4(wq, WQ + (size_t)(jq*4+m)*HIDN + c4*4);
        ld4(wk, WK + (size_t)(jq*4+m)*HIDN + c4*4);
        #pragma unroll
        for (int rr = 0; rr < 4; ++rr) {
          #pragma unroll
          for (int k = 0; k < 4; ++k) {
            Qr[rr][k] += hsq[rr][m]*wq[k];
            Vr[rr][k] += hsq[rr][m]*wk[k];
          }
        }
      }
    }
    // park V in LDS (same lane writes and later reads these addresses)
    #pragma unroll
    for (int rr = 0; rr < 4; ++rr)
      *(float4*)&vbuf[(rw+rr)*HAS + c4*4] =
          make_float4(Vr[rr][0], Vr[rr][1], Vr[rr][2], Vr[rr][3]);
  }
  {
    float bk[4]; ld4(bk, bK + c4*4);
    #pragma unroll
    for (int rr = 0; rr < 4; ++rr) {
      #pragma unroll
      for (int k = 0; k < 4; ++k) {
        Qr[rr][k] *= (1.0f/256.0f);   // bake NF^2: logit = -(Qr*Kr)
        Kr[rr][k]   = bk[k];
        MSGr[rr][k] = 0.f;
      }
    }
  }
  lds_fence();

  // ---------------- token recurrence (wave-private; zero block barriers) ----------------
  for (int it = 0; it < TT; ++it) {
    if (it > 0) {
      const float* Wr = WK + (size_t)((it-1)*32)*HIDN + c4*4;
      #pragma unroll 2
      for (int cq = 0; cq < 8; ++cq) {
        float tq[4][4];
        #pragma unroll
        for (int rr = 0; rr < 4; ++rr) ld4(tq[rr], &tokbuf[(rw+rr)*TBSTR + cq*4]);
        #pragma unroll
        for (int m = 0; m < 4; ++m) {
          float wv[4]; ld4(wv, Wr + (size_t)(cq*4+m)*HIDN);
          #pragma unroll
          for (int rr = 0; rr < 4; ++rr) {
            #pragma unroll
            for (int k = 0; k < 4; ++k) Kr[rr][k] += tq[rr][m]*wv[k];
          }
        }
      }
    }

    // eps prefetch for this lane's sampling row
    float ep[2];
    ld2(ep, eps + ((size_t)it*Btot + rowbase + rw + rp)*32 + dp*2);

    // --- softmax(-(Q*K)) without max-sub (|logit|<~2e-3); store e*V; 1/s in ivbuf ---
    #pragma unroll
    for (int rr = 0; rr < 4; ++rr) {
      float e[4]; float s = 0.f;
      #pragma unroll
      for (int k = 0; k < 4; ++k) { e[k] = __expf(-(Qr[rr][k]*Kr[rr][k])); s += e[k]; }
      #pragma unroll
      for (int off = 32; off >= 1; off >>= 1) s += __shfl_xor(s, off);
      if (c4 == rr) ivbuf[rw+rr] = 1.0f / s;
      float vv[4];
      ld4(vv, &vbuf[(rw+rr)*HAS + c4*4]);   // own-lane V readback
      *(float4*)&ha[(rw+rr)*HAS + c4*4] =
          make_float4(e[0]*vv[0], e[1]*vv[1], e[2]*vv[2], e[3]*vv[3]);
    }
    lds_fence();

    // --- GEMV (1 row x 2 dims/thread, reg-double-buffered weight stream) ---
    float mu[2]={0,0}, lv[2]={0,0};
    {
      const float* wmv = ws + WS_WMV_F + dp*4;   // + j*64 per weight row j
      const float* har = &ha[(rw+rp)*HAS];
      float4 wb0[4], wb1[4];
      #pragma unroll
      for (int u = 0; u < 4; ++u) wb0[u] = *(const float4*)(wmv + (size_t)u*64);
      #pragma unroll 1
      for (int bb = 0; bb < 32; ++bb) {
        {   // batch b = 2bb (j = 4b..4b+3, weights in wb0); prefetch b+1 into wb1
          const int b = 2*bb;
          float4 h4 = *(const float4*)(har + b*4);
          const float* wp = wmv + (size_t)(b+1)*256;
          #pragma unroll
          for (int u = 0; u < 4; ++u) wb1[u] = *(const float4*)(wp + (size_t)u*64);
          fma4(wb0[0], h4.x, mu, lv);
          fma4(wb0[1], h4.y, mu, lv);
          fma4(wb0[2], h4.z, mu, lv);
          fma4(wb0[3], h4.w, mu, lv);
        }
        {   // batch b = 2bb+1 (weights in wb1); prefetch b+1 into wb0
          const int b = 2*bb+1;
          float4 h4 = *(const float4*)(har + b*4);
          if (bb < 31) {
            const float* wp = wmv + (size_t)(b+1)*256;
            #pragma unroll
            for (int u = 0; u < 4; ++u) wb0[u] = *(const float4*)(wp + (size_t)u*64);
          }
          fma4(wb1[0], h4.x, mu, lv);
          fma4(wb1[1], h4.y, mu, lv);
          fma4(wb1[2], h4.z, mu, lv);
          fma4(wb1[3], h4.w, mu, lv);
        }
      }
    }
    // --- sample + quantize via sorted scan (global, L2-hot, NCELL=512) ---
    {
      float ivr = ivbuf[rw+rp];
      float msk = 1.0f - finbuf[rw+rp];
      const unsigned short* lutg = (const unsigned short*)(ws + WS_LUT_F);
      float md[2];
      #pragma unroll
      for (int d = 0; d < 2; ++d) {
        const int dim = 2*dp + d;
        const float* sp = ws + dim*SVS;
        float muv = mu[d]*ivr + bm[d];
        float lvv = lv[d]*ivr + bv[d];
        float x   = ep[d]*__expf(0.5f*lvv) + muv;
        int c = (int)((x - dbr[d]) * dsr[d]);
        c = min(max(c, 0), NCELL-1);
        int idx = (int)lutg[dim*NCELL + c];
        float v = sp[idx];
        while (v < x) { ++idx; v = sp[idx]; }   // pads +INF -> terminates
        float dn = v - x;
        float dpv = (idx > 0) ? (x - sp[idx-1]) : 3.0e38f;
        md[d] = fminf(dn, dpv);
      }
      *(float2*)&tokbuf[(rw+rp)*TBSTR + dp*2] = make_float2(md[0]*md[0]*msk, md[1]*md[1]*msk);
    }
    lds_fence();

    // --- hit detection + message update ---
    {
      float tokr[4][4];
      #pragma unroll
      for (int rr = 0; rr < 4; ++rr) ld4(tokr[rr], &tokbuf[(rw+rr)*TBSTR + d0u]);
      unsigned newfin = fin;
      #pragma unroll
      for (int rr = 0; rr < 4; ++rr) {
        float pd = 0.f, ed = 0.f;
        #pragma unroll
        for (int k = 0; k < 4; ++k) { float dm = tokr[rr][k]-MSGr[rr][k]; pd += dm*dm; }
        if (tg == 0) {
          #pragma unroll
          for (int k = 0; k < 4; ++k) { float de = tokr[rr][k]-eosv[k]; ed += de*de; }
        }
        pd += __shfl_xor(pd, 1); ed += __shfl_xor(ed, 1);
        pd += __shfl_xor(pd, 2); ed += __shfl_xor(ed, 2);
        pd += __shfl_xor(pd, 4); ed += __shfl_xor(ed, 4);
        bool lane_hit = (tg < it && pd < EPSI) || (tg == 0 && ed < EPSI);
        bool hit = (__ballot(lane_hit) != 0ull);
        if (hit) {
          if ((tg == it) && !((fin >> rr) & 1u)) {
            #pragma unroll
            for (int k = 0; k < 4; ++k) tokr[rr][k] = eosv[k];
          }
          newfin |= (1u << rr);
        }
        if (tg == it) {
          #pragma unroll
          for (int k = 0; k < 4; ++k) MSGr[rr][k] = tokr[rr][k];
        }
      }
      if (tg == it) {
        #pragma unroll
        for (int rr = 0; rr < 4; ++rr)
          *(float4*)&tokbuf[(rw+rr)*TBSTR + d0u] =
              make_float4(MSGr[rr][0], MSGr[rr][1], MSGr[rr][2], MSGr[rr][3]);
      }
      if (c4 < 4) finbuf[rw+c4] = ((newfin >> c4) & 1u) ? 1.f : 0.f;
      fin = newfin;
    }
    lds_fence();
  }

  // ---------------- final: comm sum (2 waves/group) + two block-coop GEMVs + relu ----------------
  __syncthreads();                 // all waves done with ha before aliasing
  float* partial = ha;             // rows 0..3: per-wave message sums /7
  float* o1      = ha + 4*HAS;     // rows 4..5: intermediate (2 groups)
  {
    float cs[4] = {0,0,0,0};
    #pragma unroll
    for (int rr = 0; rr < 4; ++rr) {
      #pragma unroll
      for (int k = 0; k < 4; ++k) cs[k] += MSGr[rr][k];
    }
    const float i7 = 1.0f/7.0f;
    *(float4*)&partial[w*HAS + c4*4] = make_float4(cs[0]*i7, cs[1]*i7, cs[2]*i7, cs[3]*i7);
  }
  __syncthreads();
  {
    float bs = bsum[t];
    float a1[2] = {bs, bs};
    #pragma unroll 2
    for (int jq = 0; jq < 64; ++jq) {
      float w4[4];
      #pragma unroll
      for (int m = 0; m < 4; ++m) w4[m] = Wsum[(size_t)(jq*4+m)*HIDN + t];
      #pragma unroll
      for (int g = 0; g < 2; ++g) {
        float ca[4], cb[4];
        ld4(ca, &partial[(2*g)*HAS + jq*4]);     // uniform broadcast
        ld4(cb, &partial[(2*g+1)*HAS + jq*4]);
        a1[g] += (ca[0]+cb[0])*w4[0] + (ca[1]+cb[1])*w4[1]
               + (ca[2]+cb[2])*w4[2] + (ca[3]+cb[3])*w4[3];
      }
    }
    o1[t] = a1[0]; o1[HAS + t] = a1[1];
  }
  __syncthreads();
  {
    float bh = bhead[t];
    float a2[2] = {bh, bh};
    #pragma unroll 2
    for (int jq = 0; jq < 64; ++jq) {
      float w4[4];
      #pragma unroll
      for (int m = 0; m < 4; ++m) w4[m] = Whead[(size_t)(jq*4+m)*HIDN + t];
      #pragma unroll
      for (int g = 0; g < 2; ++g) {
        float c[4]; ld4(c, &o1[g*HAS + jq*4]);
        a2[g] += c[0]*w4[0] + c[1]*w4[1] + c[2]*w4[2] + c[3]*w4[3];
      }
    }
    #pragma unroll
    for (int g = 0; g < 2; ++g) {
      float r = fmaxf(a2[g], 0.f);
      #pragma unroll
      for (int rr = 0; rr < 8; ++rr)
        out[(size_t)(rowbase + g*8 + rr)*HIDN + t] = r;
    }
  }
}

extern "C" void kernel_launch(void* const* d_in, const int* in_sizes, int n_in,
                              void* d_out, int out_size, void* d_ws, size_t ws_size,
                              hipStream_t stream) {
    const float* hs    = (const float*)d_in[0];
    const float* eps   = (const float*)d_in[1];
    const float* WQ    = (const float*)d_in[2];
    const float* bQ    = (const float*)d_in[3];
    const float* WK    = (const float*)d_in[4];
    const float* bK    = (const float*)d_in[5];
    const float* Wmu   = (const float*)d_in[6];
    const float* bmu   = (const float*)d_in[7];
    const float* Wvar  = (const float*)d_in[8];
    const float* bvar  = (const float*)d_in[9];
    const float* vocab = (const float*)d_in[10];
    const float* Wsum  = (const float*)d_in[11];
    const float* bsum  = (const float*)d_in[12];
    const float* Whead = (const float*)d_in[13];
    const float* bhead = (const float*)d_in[14];
    float* o = (float*)d_out;
    float* wsf = (float*)d_ws;
    int Btot = in_sizes[0] / HIDN;
    hipLaunchKernelGGL(sort_vocab, dim3(32), dim3(256), 0, stream, vocab, Wmu, Wvar, wsf);
    hipLaunchKernelGGL(mac_fused, dim3(Btot / ROWSB), dim3(256), 0, stream,
                       hs, eps, WQ, bQ, WK, bK, Wmu, bmu, Wvar, bvar,
                       vocab, Wsum, bsum, Whead, bhead, wsf, o, Btot);
}

// Round 10
// 353.051 us; speedup vs baseline: 1.4455x; 1.4455x over previous
//
#include <hip/hip_runtime.h>

#define ROWSB 32     // rows per block; 4 waves x 8 rows (wave == agent group)
#define HIDN 256
#define TT 8
#define EPSI 1e-6f
#define HAS 260      // ha/vbuf row stride (floats)
#define SVS 260      // sorted-vocab row stride in ws (257 used + 3 INF pad)
#define TBSTR 40
#define NCELL 512
#define WS_LUT_F   (32*SVS)                 // ushort lut[32][512] == 8192 floats
#define WS_DINFO_F (32*SVS + 8192)          // float2 dinfo[32] (base, scale)
#define WS_WMV_F   (32*SVS + 8192 + 64)     // interleaved [j][d][(mu,var)] = 16384 floats

__device__ __forceinline__ void ld4(float* d, const float* p) {
  float4 v = *(const float4*)p;
  d[0] = v.x; d[1] = v.y; d[2] = v.z; d[3] = v.w;
}
__device__ __forceinline__ void ld2(float* d, const float* p) {
  float2 v = *(const float2*)p;
  d[0] = v.x; d[1] = v.y;
}
// Order own-wave LDS write->read without draining the global-load (vmcnt) queue.
__device__ __forceinline__ void lds_fence() {
  asm volatile("s_waitcnt lgkmcnt(0)" ::: "memory");
}
// 8 FMAs for one j: wv = (mu[d0],var[d0],mu[d1],var[d1]); h0/h1 = ha[row0/1][j]
__device__ __forceinline__ void fma8(float4 wv, float h0, float h1,
                                     float* mu0, float* lv0, float* mu1, float* lv1) {
  mu0[0] += h0*wv.x; lv0[0] += h0*wv.y; mu0[1] += h0*wv.z; lv0[1] += h0*wv.w;
  mu1[0] += h1*wv.x; lv1[0] += h1*wv.y; mu1[1] += h1*wv.z; lv1[1] += h1*wv.w;
}

// ---- DPP cross-lane reductions (pure VALU, zero lgkm; replaces __shfl_xor chains) ----
#define DPP_ADD(x, ctrl) \
  (x) += __int_as_float(__builtin_amdgcn_update_dpp(0, __float_as_int(x), (ctrl), 0xf, 0xf, true))
// Full 64-lane sum -> uniform (SGPR) via classic gfx9 sequence.
__device__ __forceinline__ float wave_sum64(float x) {
  DPP_ADD(x, 0x111);  // row_shr:1
  DPP_ADD(x, 0x112);  // row_shr:2
  DPP_ADD(x, 0x114);  // row_shr:4
  DPP_ADD(x, 0x118);  // row_shr:8  -> lane15/31/47/63 hold 16-lane row sums
  DPP_ADD(x, 0x142);  // row_bcast:15 -> lane31 = sum(0..31), lane63 = sum(32..63)
  DPP_ADD(x, 0x143);  // row_bcast:31 -> lane63 = sum(0..63)
  return __int_as_float(__builtin_amdgcn_readlane(__float_as_int(x), 63));
}
// 8-lane group sum: valid ONLY at top lane of each group (c4 & 7) == 7.
// (row_shr stays within 16-lane rows; groups align with row halves -> no cross-row loss.)
__device__ __forceinline__ float grp8_sum(float x) {
  DPP_ADD(x, 0x111);
  DPP_ADD(x, 0x112);
  DPP_ADD(x, 0x114);
  return x;
}

// ---------- pre-pass: per-dim bitonic sort + 512-cell LUT + (mu,var) weight interleave ----------
__global__ __launch_bounds__(256)
void sort_vocab(const float* __restrict__ vocab,
                const float* __restrict__ Wmu, const float* __restrict__ Wvar,
                float* __restrict__ ws) {
  __shared__ float arr[512];
  const int d = blockIdx.x;
  const int t = threadIdx.x;
  ws[WS_WMV_F + ((size_t)t*32 + d)*2 + 0] = Wmu[(size_t)t*32 + d];
  ws[WS_WMV_F + ((size_t)t*32 + d)*2 + 1] = Wvar[(size_t)t*32 + d];
  arr[t] = (t < 257) ? vocab[t*32 + d] : 3.0e38f;
  arr[t+256] = (t == 0) ? vocab[256*32 + d] : 3.0e38f;
  __syncthreads();
  for (int k = 2; k <= 512; k <<= 1) {
    for (int j = k >> 1; j > 0; j >>= 1) {
      #pragma unroll
      for (int h = 0; h < 2; ++h) {
        int i = t + h*256;
        int ixj = i ^ j;
        if (ixj > i) {
          float a = arr[i], b = arr[ixj];
          bool up = ((i & k) == 0);
          if ((a > b) == up) { arr[i] = b; arr[ixj] = a; }
        }
      }
      __syncthreads();
    }
  }
  #pragma unroll
  for (int h = 0; h < 2; ++h) {
    int i = t + h*256;
    if (i < SVS) ws[d*SVS + i] = (i < 257) ? arr[i] : 3.0e38f;
  }
  float base = arr[0];
  float maxv = arr[256];
  float scale = (float)NCELL / fmaxf(maxv - base, 1e-30f);
  if (t == 0) {
    float2* dinfo = (float2*)(ws + WS_DINFO_F);
    dinfo[d] = make_float2(base, scale);
  }
  #pragma unroll
  for (int h = 0; h < 2; ++h) {
    int cell = t + h*256;
    float target = base + (float)cell * (maxv - base) * (1.0f/(float)NCELL);
    int lo = 0, hi = 257;
    while (lo < hi) { int mid = (lo+hi)>>1; if (arr[mid] < target) lo = mid+1; else hi = mid; }
    ((unsigned short*)(ws + WS_LUT_F))[d*NCELL + cell] = (unsigned short)lo;
  }
}

// ---------- main fused kernel: 8 rows/wave (r7 structure, confirmed best) ----------
// r10: r7 + DPP cross-lane reductions. r9 closed the occupancy route: 4-rows/wave ran
// clean (VGPR 92, zero spills) but occupancy stayed 2 blocks/CU and total VALU time
// GREW 26% (amortization loss) -> 460us. r7's 97k VALU instr/wave at 55.7% busy has a
// 162us 100%-busy floor; the lever is the 44% stall fraction. This round: replace the
// ~96 __shfl_xor per iteration (ds_swizzle, lgkm-latency chains right before lgkmcnt(0)
// fences) with DPP VALU reductions (zero lgkm): softmax 64-lane sum via
// row_shr1/2/4/8+row_bcast15/31+readlane; hit-detect 8-lane sums via row_shr1/2/4 read
// at top lane only (lower lanes hold contaminated partials -> (c4&7)==7 predicate
// before the ballot). FP sum order changes (~1e-7 perturbation; r3's kill level was
// 1e-5 -- two orders of margin).
__global__ __launch_bounds__(256, 2)
void mac_fused(const float* __restrict__ hs, const float* __restrict__ eps,
               const float* __restrict__ WQ, const float* __restrict__ bQ,
               const float* __restrict__ WK, const float* __restrict__ bK,
               const float* __restrict__ Wmu, const float* __restrict__ bmu,
               const float* __restrict__ Wvar, const float* __restrict__ bvar,
               const float* __restrict__ vocab,
               const float* __restrict__ Wsum, const float* __restrict__ bsum,
               const float* __restrict__ Whead, const float* __restrict__ bhead,
               const float* __restrict__ ws, float* __restrict__ out, int Btot)
{
  // 71,936 B LDS -> 2 blocks/CU
  __shared__ __align__(16) float ha[ROWSB*HAS];       // wave-private rows; end: comm/o1 alias
  __shared__ __align__(16) float vbuf[ROWSB*HAS];     // V, wave-private, written once
  __shared__ __align__(16) float tokbuf[ROWSB*TBSTR]; // wave-private rows
  __shared__ float ivbuf[ROWSB], finbuf[ROWSB];       // wave-private rows

  const int t   = threadIdx.x;
  const int c4  = t & 63;
  const int w   = t >> 6;         // wave id; rows w*8..w*8+7 (one agent group)
  const int rp  = t >> 4;         // sampling row-pair: rows 2rp, 2rp+1 (in own octet)
  const int dp  = t & 15;         // sampling dim-pair: dims 2dp, 2dp+1
  const int d0u = (c4 << 2) & 31;
  const int tg  = c4 >> 3;        // token slot of this thread's cols
  const int rowbase = blockIdx.x * ROWSB;

  float Qr[8][4], Kr[8][4], MSGr[8][4];
  float eosv[4];
  unsigned fin = 0u;

  // ---------------- staging (all wave-private) ----------------
  {
    const float* hp = hs + (size_t)(rowbase + w*8)*HIDN + c4*4;
    #pragma unroll
    for (int rr = 0; rr < 8; ++rr)
      *(float4*)&ha[(w*8+rr)*HAS + c4*4] = *(const float4*)(hp + (size_t)rr*HIDN);
  }
  if (c4 < 8) finbuf[w*8 + c4] = 0.f;
  ld4(eosv, vocab + 256*32 + d0u);
  float dbr[2], dsr[2];
  {
    float t0[4];
    ld4(t0, ws + WS_DINFO_F + dp*4);   // dinfo[2dp], dinfo[2dp+1]
    dbr[0]=t0[0]; dsr[0]=t0[1]; dbr[1]=t0[2]; dsr[1]=t0[3];
  }
  float bm[2], bv[2];
  ld2(bm, bmu + dp*2); ld2(bv, bvar + dp*2);
  lds_fence();   // own-wave ha writes ordered before cross-lane reads

  // ------------- initial GEMM: Q = hs@WQ + bQ ; V = hs@WK + bK (V -> vbuf) -------------
  {
    float Vr[8][4];
    {
      float bq[4], bk[4];
      ld4(bq, bQ + c4*4); ld4(bk, bK + c4*4);
      #pragma unroll
      for (int rr = 0; rr < 8; ++rr) {
        #pragma unroll
        for (int k = 0; k < 4; ++k) { Qr[rr][k] = bq[k]; Vr[rr][k] = bk[k]; }
      }
    }
    #pragma unroll 2
    for (int jq = 0; jq < 64; ++jq) {
      float hsq[8][4];
      #pragma unroll
      for (int rr = 0; rr < 8; ++rr) ld4(hsq[rr], &ha[(w*8+rr)*HAS + jq*4]);
      #pragma unroll
      for (int m = 0; m < 4; ++m) {
        float wq[4], wk[4];
        ld4(wq, WQ + (size_t)(jq*4+m)*HIDN + c4*4);
        ld4(wk, WK + (size_t)(jq*4+m)*HIDN + c4*4);
        #pragma unroll
        for (int rr = 0; rr < 8; ++rr) {
          #pragma unroll
          for (int k = 0; k < 4; ++k) {
            Qr[rr][k] += hsq[rr][m]*wq[k];
            Vr[rr][k] += hsq[rr][m]*wk[k];
          }
        }
      }
    }
    // park V in LDS (same lane writes and later reads these addresses)
    #pragma unroll
    for (int rr = 0; rr < 8; ++rr)
      *(float4*)&vbuf[(w*8+rr)*HAS + c4*4] =
          make_float4(Vr[rr][0], Vr[rr][1], Vr[rr][2], Vr[rr][3]);
  }
  {
    float bk[4]; ld4(bk, bK + c4*4);
    #pragma unroll
    for (int rr = 0; rr < 8; ++rr) {
      #pragma unroll
      for (int k = 0; k < 4; ++k) {
        Qr[rr][k] *= (1.0f/256.0f);   // bake NF^2: logit = -(Qr*Kr)
        Kr[rr][k]   = bk[k];
        MSGr[rr][k] = 0.f;
      }
    }
  }
  lds_fence();

  // ---------------- token recurrence (wave-private; zero block barriers) ----------------
  for (int it = 0; it < TT; ++it) {
    if (it > 0) {
      const float* Wr = WK + (size_t)((it-1)*32)*HIDN + c4*4;
      #pragma unroll 2
      for (int cq = 0; cq < 8; ++cq) {
        float tq[8][4];
        #pragma unroll
        for (int rr = 0; rr < 8; ++rr) ld4(tq[rr], &tokbuf[(w*8+rr)*TBSTR + cq*4]);
        #pragma unroll
        for (int m = 0; m < 4; ++m) {
          float wv[4]; ld4(wv, Wr + (size_t)(cq*4+m)*HIDN);
          #pragma unroll
          for (int rr = 0; rr < 8; ++rr) {
            #pragma unroll
            for (int k = 0; k < 4; ++k) Kr[rr][k] += tq[rr][m]*wv[k];
          }
        }
      }
    }

    // eps prefetch for both sampling rows
    float ep0[2], ep1[2];
    ld2(ep0, eps + ((size_t)it*Btot + rowbase + 2*rp)*32 + dp*2);
    ld2(ep1, eps + ((size_t)it*Btot + rowbase + 2*rp+1)*32 + dp*2);

    // --- softmax(-(Q*K)) without max-sub (|logit|<~2e-3); store e*V; 1/s in ivbuf ---
    // DPP wave-sum: 6 VALU adds + readlane per row, zero lgkm (was 6 ds_swizzle).
    #pragma unroll
    for (int rr = 0; rr < 8; ++rr) {
      float e[4]; float p = 0.f;
      #pragma unroll
      for (int k = 0; k < 4; ++k) { e[k] = __expf(-(Qr[rr][k]*Kr[rr][k])); p += e[k]; }
      float s = wave_sum64(p);           // uniform across the wave
      if (c4 == rr) ivbuf[w*8+rr] = 1.0f / s;
      float vv[4];
      ld4(vv, &vbuf[(w*8+rr)*HAS + c4*4]);   // own-lane V readback
      *(float4*)&ha[(w*8+rr)*HAS + c4*4] =
          make_float4(e[0]*vv[0], e[1]*vv[1], e[2]*vv[2], e[3]*vv[3]);
    }
    lds_fence();

    // --- GEMV (2 rows x 2 dims/thread; 4-j double-buffered weight stream, 32 regs) ---
    float mu0[2]={0,0}, lv0[2]={0,0}, mu1[2]={0,0}, lv1[2]={0,0};
    {
      const float* wmv  = ws + WS_WMV_F + dp*4;   // + j*64 per weight row j
      const float* har0 = &ha[(2*rp)*HAS];
      const float* har1 = &ha[(2*rp+1)*HAS];
      float4 wb0[4], wb1[4];
      #pragma unroll
      for (int u = 0; u < 4; ++u) wb0[u] = *(const float4*)(wmv + (size_t)u*64);
      #pragma unroll 1
      for (int bb = 0; bb < 32; ++bb) {
        {   // window b = 2bb (j = 4b..4b+3, weights in wb0); prefetch b+1 into wb1
          const int b = 2*bb;
          float4 h0 = *(const float4*)(har0 + b*4);
          float4 h1 = *(const float4*)(har1 + b*4);
          const float* wp = wmv + (size_t)(b+1)*256;
          #pragma unroll
          for (int u = 0; u < 4; ++u) wb1[u] = *(const float4*)(wp + (size_t)u*64);
          fma8(wb0[0], h0.x, h1.x, mu0, lv0, mu1, lv1);
          fma8(wb0[1], h0.y, h1.y, mu0, lv0, mu1, lv1);
          fma8(wb0[2], h0.z, h1.z, mu0, lv0, mu1, lv1);
          fma8(wb0[3], h0.w, h1.w, mu0, lv0, mu1, lv1);
        }
        {   // window b = 2bb+1 (weights in wb1); prefetch b+1 into wb0
          const int b = 2*bb+1;
          float4 h0 = *(const float4*)(har0 + b*4);
          float4 h1 = *(const float4*)(har1 + b*4);
          if (bb < 31) {
            const float* wp = wmv + (size_t)(b+1)*256;
            #pragma unroll
            for (int u = 0; u < 4; ++u) wb0[u] = *(const float4*)(wp + (size_t)u*64);
          }
          fma8(wb1[0], h0.x, h1.x, mu0, lv0, mu1, lv1);
          fma8(wb1[1], h0.y, h1.y, mu0, lv0, mu1, lv1);
          fma8(wb1[2], h0.z, h1.z, mu0, lv0, mu1, lv1);
          fma8(wb1[3], h0.w, h1.w, mu0, lv0, mu1, lv1);
        }
      }
    }
    // --- sample + quantize via sorted scan (global, L2-hot, NCELL=512) ---
    {
      float ivr0 = ivbuf[2*rp],  ivr1 = ivbuf[2*rp+1];
      float msk0 = 1.0f - finbuf[2*rp], msk1 = 1.0f - finbuf[2*rp+1];
      const unsigned short* lutg = (const unsigned short*)(ws + WS_LUT_F);
      float md0[2], md1[2];
      #pragma unroll
      for (int d = 0; d < 2; ++d) {
        const int dim = 2*dp + d;
        const float* sp = ws + dim*SVS;
        {
          float mu = mu0[d]*ivr0 + bm[d];
          float lv = lv0[d]*ivr0 + bv[d];
          float x  = ep0[d]*__expf(0.5f*lv) + mu;
          int c = (int)((x - dbr[d]) * dsr[d]);
          c = min(max(c, 0), NCELL-1);
          int idx = (int)lutg[dim*NCELL + c];
          float v = sp[idx];
          while (v < x) { ++idx; v = sp[idx]; }   // pads +INF -> terminates
          float dn = v - x;
          float dpv = (idx > 0) ? (x - sp[idx-1]) : 3.0e38f;
          md0[d] = fminf(dn, dpv);
        }
        {
          float mu = mu1[d]*ivr1 + bm[d];
          float lv = lv1[d]*ivr1 + bv[d];
          float x  = ep1[d]*__expf(0.5f*lv) + mu;
          int c = (int)((x - dbr[d]) * dsr[d]);
          c = min(max(c, 0), NCELL-1);
          int idx = (int)lutg[dim*NCELL + c];
          float v = sp[idx];
          while (v < x) { ++idx; v = sp[idx]; }
          float dn = v - x;
          float dpv = (idx > 0) ? (x - sp[idx-1]) : 3.0e38f;
          md1[d] = fminf(dn, dpv);
        }
      }
      *(float2*)&tokbuf[(2*rp)*TBSTR + dp*2]   = make_float2(md0[0]*md0[0]*msk0, md0[1]*md0[1]*msk0);
      *(float2*)&tokbuf[(2*rp+1)*TBSTR + dp*2] = make_float2(md1[0]*md1[0]*msk1, md1[1]*md1[1]*msk1);
    }
    lds_fence();

    // --- hit detection + message update (DPP 8-lane sums, top-lane ballot) ---
    {
      float tokr[8][4];
      #pragma unroll
      for (int rr = 0; rr < 8; ++rr) ld4(tokr[rr], &tokbuf[(w*8+rr)*TBSTR + d0u]);
      const bool top = ((c4 & 7) == 7);   // only top lane of each 8-lane tg group has clean sums
      unsigned newfin = fin;
      #pragma unroll
      for (int rr = 0; rr < 8; ++rr) {
        float pd = 0.f, ed = 0.f;
        #pragma unroll
        for (int k = 0; k < 4; ++k) { float dm = tokr[rr][k]-MSGr[rr][k]; pd += dm*dm; }
        if (tg == 0) {
          #pragma unroll
          for (int k = 0; k < 4; ++k) { float de = tokr[rr][k]-eosv[k]; ed += de*de; }
        }
        pd = grp8_sum(pd);   // valid at top lanes only
        ed = grp8_sum(ed);
        bool lane_hit = top && ((tg < it && pd < EPSI) || (tg == 0 && ed < EPSI));
        bool hit = (__ballot(lane_hit) != 0ull);
        if (hit) {
          if ((tg == it) && !((fin >> rr) & 1u)) {
            #pragma unroll
            for (int k = 0; k < 4; ++k) tokr[rr][k] = eosv[k];
          }
          newfin |= (1u << rr);
        }
        if (tg == it) {
          #pragma unroll
          for (int k = 0; k < 4; ++k) MSGr[rr][k] = tokr[rr][k];
        }
      }
      if (tg == it) {
        #pragma unroll
        for (int rr = 0; rr < 8; ++rr)
          *(float4*)&tokbuf[(w*8+rr)*TBSTR + d0u] =
              make_float4(MSGr[rr][0], MSGr[rr][1], MSGr[rr][2], MSGr[rr][3]);
      }
      if (c4 < 8) finbuf[w*8+c4] = ((newfin >> c4) & 1u) ? 1.f : 0.f;
      fin = newfin;
    }
    lds_fence();
  }

  // ---------------- final: comm sum + two block-coop GEMVs + relu ----------------
  __syncthreads();                 // all waves done with ha before aliasing
  float* commb = ha;               // [4][HAS] rows 0..3
  float* o1    = ha + 4*HAS;       // [4][HAS] rows 4..7
  {
    float cs[4] = {0,0,0,0};
    #pragma unroll
    for (int rr = 0; rr < 8; ++rr) {
      #pragma unroll
      for (int k = 0; k < 4; ++k) cs[k] += MSGr[rr][k];
    }
    const float i7 = 1.0f/7.0f;
    *(float4*)&commb[w*HAS + c4*4] = make_float4(cs[0]*i7, cs[1]*i7, cs[2]*i7, cs[3]*i7);
  }
  __syncthreads();
  {
    float bs = bsum[t];
    float a1[4] = {bs, bs, bs, bs};
    #pragma unroll 2
    for (int jq = 0; jq < 64; ++jq) {
      float w4[4];
      #pragma unroll
      for (int m = 0; m < 4; ++m) w4[m] = Wsum[(size_t)(jq*4+m)*HIDN + t];
      #pragma unroll
      for (int g = 0; g < 4; ++g) {
        float c[4]; ld4(c, &commb[g*HAS + jq*4]);   // uniform broadcast
        a1[g] += c[0]*w4[0] + c[1]*w4[1] + c[2]*w4[2] + c[3]*w4[3];
      }
    }
    #pragma unroll
    for (int g = 0; g < 4; ++g) o1[g*HAS + t] = a1[g];
  }
  __syncthreads();
  {
    float bh = bhead[t];
    float a2[4] = {bh, bh, bh, bh};
    #pragma unroll 2
    for (int jq = 0; jq < 64; ++jq) {
      float w4[4];
      #pragma unroll
      for (int m = 0; m < 4; ++m) w4[m] = Whead[(size_t)(jq*4+m)*HIDN + t];
      #pragma unroll
      for (int g = 0; g < 4; ++g) {
        float c[4]; ld4(c, &o1[g*HAS + jq*4]);
        a2[g] += c[0]*w4[0] + c[1]*w4[1] + c[2]*w4[2] + c[3]*w4[3];
      }
    }
    #pragma unroll
    for (int g = 0; g < 4; ++g) {
      float r = fmaxf(a2[g], 0.f);
      #pragma unroll
      for (int rr = 0; rr < 8; ++rr)
        out[(size_t)(rowbase + g*8 + rr)*HIDN + t] = r;
    }
  }
}

extern "C" void kernel_launch(void* const* d_in, const int* in_sizes, int n_in,
                              void* d_out, int out_size, void* d_ws, size_t ws_size,
                              hipStream_t stream) {
    const float* hs    = (const float*)d_in[0];
    const float* eps   = (const float*)d_in[1];
    const float* WQ    = (const float*)d_in[2];
    const float* bQ    = (const float*)d_in[3];
    const float* WK    = (const float*)d_in[4];
    const float* bK    = (const float*)d_in[5];
    const float* Wmu   = (const float*)d_in[6];
    const float* bmu   = (const float*)d_in[7];
    const float* Wvar  = (const float*)d_in[8];
    const float* bvar  = (const float*)d_in[9];
    const float* vocab = (const float*)d_in[10];
    const float* Wsum  = (const float*)d_in[11];
    const float* bsum  = (const float*)d_in[12];
    const float* Whead = (const float*)d_in[13];
    const float* bhead = (const float*)d_in[14];
    float* o = (float*)d_out;
    float* wsf = (float*)d_ws;
    int Btot = in_sizes[0] / HIDN;
    hipLaunchKernelGGL(sort_vocab, dim3(32), dim3(256), 0, stream, vocab, Wmu, Wvar, wsf);
    hipLaunchKernelGGL(mac_fused, dim3(Btot / ROWSB), dim3(256), 0, stream,
                       hs, eps, WQ, bQ, WK, bK, Wmu, bmu, Wvar, bvar,
                       vocab, Wsum, bsum, Whead, bhead, wsf, o, Btot);
}